// Round 1
// baseline (827.247 us; speedup 1.0000x reference)
//
#include <hip/hip_runtime.h>

// Problem constants (match reference setup_inputs)
#define N_VAR (1 << 22)   // variable nodes
#define DV    4
#define M_CHK (1 << 21)   // check nodes
#define DC    8
#define N_ITER 5

// out[i] = llr0[i]  (vectorized float4 copy; N_VAR divisible by 4*256)
__global__ __launch_bounds__(256) void nbp_init_out(const float4* __restrict__ llr0,
                                                    float4* __restrict__ out) {
    int i = blockIdx.x * blockDim.x + threadIdx.x;
    out[i] = llr0[i];
}

// One thread per check node: 8 messages live in registers across all 5
// iterations (non-extrinsic min-sum + permutation scatter => checks are
// fully independent until the final per-variable sum).
__global__ __launch_bounds__(256) void nbp_check_kernel(const float* __restrict__ llr0,
                                                        const float* __restrict__ gamma_p,
                                                        const int* __restrict__ cn_adj,
                                                        float* __restrict__ out) {
    const int m = blockIdx.x * blockDim.x + threadIdx.x;
    const float gamma = gamma_p[0];

    // 8 flat edge indices for this check, coalesced 32B load
    const int4* adj = reinterpret_cast<const int4*>(cn_adj) + (size_t)m * 2;
    int4 a0 = adj[0];
    int4 a1 = adj[1];
    int e[DC] = {a0.x, a0.y, a0.z, a0.w, a1.x, a1.y, a1.z, a1.w};

    // Gather llr0 of each edge's variable (edge e -> variable e >> 2)
    float l[DC];
    float msg[DC];
#pragma unroll
    for (int d = 0; d < DC; ++d) {
        l[d] = llr0[e[d] >> 2];
    }

    // Iteration 1 peeled: msg==0 -> min|msg|==0 -> c2v = gamma*1*0 = 0 exactly,
    // so msg_new = llr0 + 0 - 0 = llr0.
#pragma unroll
    for (int d = 0; d < DC; ++d) msg[d] = l[d];

#pragma unroll
    for (int it = 1; it < N_ITER; ++it) {
        // sign product with the reference's +1e-12 shift (jnp.sign semantics)
        float s = 1.0f;
        float mn = fabsf(msg[0]);
#pragma unroll
        for (int d = 0; d < DC; ++d) {
            float t = msg[d] + 1e-12f;
            s *= (t > 0.0f) ? 1.0f : ((t < 0.0f) ? -1.0f : 0.0f);
            if (d > 0) mn = fminf(mn, fabsf(msg[d]));
        }
        float c2v = gamma * s * mn;
        // v2c_new = (llr0 + c2v) - v2c  (same association as reference)
#pragma unroll
        for (int d = 0; d < DC; ++d) {
            msg[d] = (l[d] + c2v) - msg[d];
        }
    }

    // Final: out[n] = llr0[n] + sum of variable n's 4 edge messages.
    // Each variable has exactly DV=4 edges => 4 atomics per output element.
#pragma unroll
    for (int d = 0; d < DC; ++d) {
        atomicAdd(&out[e[d] >> 2], msg[d]);
    }
}

extern "C" void kernel_launch(void* const* d_in, const int* in_sizes, int n_in,
                              void* d_out, int out_size, void* d_ws, size_t ws_size,
                              hipStream_t stream) {
    const float* llr0   = (const float*)d_in[0];
    const float* gamma  = (const float*)d_in[1];
    // d_in[2] = vn_adj: only its sign is used in the reference; regular code -> no padding, unused.
    const int*   cn_adj = (const int*)d_in[3];
    float* out = (float*)d_out;

    // 1) out = llr0
    {
        int n4 = N_VAR / 4;
        nbp_init_out<<<n4 / 256, 256, 0, stream>>>((const float4*)llr0, (float4*)out);
    }
    // 2) per-check compute + atomic accumulate
    {
        nbp_check_kernel<<<M_CHK / 256, 256, 0, stream>>>(llr0, gamma, cn_adj, out);
    }
}

// Round 2
// 466.603 us; speedup vs baseline: 1.7729x; 1.7729x over previous
//
#include <hip/hip_runtime.h>

// Problem constants (match reference setup_inputs)
#define N_VAR (1 << 22)   // variable nodes
#define DV    4
#define M_CHK (1 << 21)   // check nodes
#define DC    8
#define N_ITER 5
#define E_TOT (N_VAR * DV)

// One thread per check node: 8 messages live in registers across all 5
// iterations (non-extrinsic min-sum + permutation scatter => checks are
// fully independent until the final per-variable sum).
// Final messages are PLAIN-stored to ws[e] — cn_adj is a permutation of
// [0, E), so no two checks write the same slot (no atomics needed).
__global__ __launch_bounds__(256) void nbp_check_kernel(const float* __restrict__ llr0,
                                                        const float* __restrict__ gamma_p,
                                                        const int* __restrict__ cn_adj,
                                                        float* __restrict__ ws) {
    const int m = blockIdx.x * blockDim.x + threadIdx.x;
    const float gamma = gamma_p[0];

    // 8 flat edge indices for this check, coalesced 32B load
    const int4* adj = reinterpret_cast<const int4*>(cn_adj) + (size_t)m * 2;
    int4 a0 = adj[0];
    int4 a1 = adj[1];
    int e[DC] = {a0.x, a0.y, a0.z, a0.w, a1.x, a1.y, a1.z, a1.w};

    // Gather llr0 of each edge's variable (edge e -> variable e >> 2)
    float l[DC];
    float msg[DC];
#pragma unroll
    for (int d = 0; d < DC; ++d) {
        l[d] = llr0[e[d] >> 2];
    }

    // Iteration 1 peeled: msg==0 -> min|msg|==0 -> c2v = gamma*1*0 = 0 exactly,
    // so msg_new = llr0 + 0 - 0 = llr0.
#pragma unroll
    for (int d = 0; d < DC; ++d) msg[d] = l[d];

#pragma unroll
    for (int it = 1; it < N_ITER; ++it) {
        // sign product with the reference's +1e-12 shift (jnp.sign semantics)
        float s = 1.0f;
        float mn = fabsf(msg[0]);
#pragma unroll
        for (int d = 0; d < DC; ++d) {
            float t = msg[d] + 1e-12f;
            s *= (t > 0.0f) ? 1.0f : ((t < 0.0f) ? -1.0f : 0.0f);
            if (d > 0) mn = fminf(mn, fabsf(msg[d]));
        }
        float c2v = gamma * s * mn;
        // v2c_new = (llr0 + c2v) - v2c  (same association as reference)
#pragma unroll
        for (int d = 0; d < DC; ++d) {
            msg[d] = (l[d] + c2v) - msg[d];
        }
    }

    // Scattered plain stores (no RMW): every edge slot written exactly once.
#pragma unroll
    for (int d = 0; d < DC; ++d) {
        ws[e[d]] = msg[d];
    }
}

// One thread per variable: coalesced float4 read of its 4 edge messages,
// out[n] = llr0[n] + sum.
__global__ __launch_bounds__(256) void nbp_var_reduce(const float* __restrict__ llr0,
                                                      const float4* __restrict__ ws4,
                                                      float* __restrict__ out) {
    const int n = blockIdx.x * blockDim.x + threadIdx.x;
    float4 w = ws4[n];
    out[n] = llr0[n] + (((w.x + w.y) + w.z) + w.w);
}

extern "C" void kernel_launch(void* const* d_in, const int* in_sizes, int n_in,
                              void* d_out, int out_size, void* d_ws, size_t ws_size,
                              hipStream_t stream) {
    const float* llr0   = (const float*)d_in[0];
    const float* gamma  = (const float*)d_in[1];
    // d_in[2] = vn_adj: only its sign is used in the reference; regular code -> no padding, unused.
    const int*   cn_adj = (const int*)d_in[3];
    float* out = (float*)d_out;
    float* ws  = (float*)d_ws;   // E_TOT floats = 64 MB per-edge message buffer

    // 1) per-check compute + scattered per-edge stores
    nbp_check_kernel<<<M_CHK / 256, 256, 0, stream>>>(llr0, gamma, cn_adj, ws);

    // 2) per-variable coalesced reduce: out = llr0 + sum(ws[4n..4n+3])
    nbp_var_reduce<<<N_VAR / 256, 256, 0, stream>>>(llr0, (const float4*)ws, out);
}